// Round 4
// baseline (90.985 us; speedup 1.0000x reference)
//
#include <hip/hip_runtime.h>
#include <hip/hip_bf16.h>

// Problem constants (from reference)
#define MAX_LEN_PAD 2560
#define MIN_LEN_SEG 19
#define MAX_NUM_SEG 108   // segments per batch row
#define B_ROWS      32
#define S_CAND      64
#define N_SEG       3456  // B_ROWS * MAX_NUM_SEG

// ws layout (ints): meta[0..15], seg_start[16..16+3456+pad], seg_off after
#define WS_META      0
#define WS_SEGSTART  16
#define WS_SEGOFF    (16 + 3520)

// Kernel A: single block, 1024 threads.
//  - per-batch-row exclusive cumsum of len_seg via 32-lane shfl scans (offsets)
//  - per-segment mask counts (mask is a prefix in s -> 6-step binary search
//    with the reference's exact fp32 predicate), 4 segments/thread
//  - global exclusive scan of counts via wave shfl scan + tiny LDS combine
__global__ __launch_bounds__(1024) void seg_scan_kernel(
    const int* __restrict__ len_seq, const float* __restrict__ scales_u,
    const int* __restrict__ len_seg_raw, int* __restrict__ ws)
{
    __shared__ int lenseg[N_SEG];
    __shared__ int offs[N_SEG];
    __shared__ int wavesum[24];

    int tid = threadIdx.x;
    for (int i = tid; i < N_SEG; i += 1024) lenseg[i] = len_seg_raw[i] + MIN_LEN_SEG;
    __syncthreads();

    // per-row exclusive cumsum: one 32-lane group per batch row (32 rows x 108)
    {
        int row = tid >> 5, l32 = tid & 31;
        int base = row * MAX_NUM_SEG;
        int v[4]; int sum = 0;
        #pragma unroll
        for (int j = 0; j < 4; ++j) {
            int k = l32 * 4 + j;
            v[j] = (k < MAX_NUM_SEG) ? lenseg[base + k] : 0;
            sum += v[j];
        }
        int incl = sum;
        #pragma unroll
        for (int d = 1; d < 32; d <<= 1) {
            int o = __shfl_up(incl, d, 32);
            if (l32 >= d) incl += o;
        }
        int run = incl - sum;   // exclusive base for this lane's chunk
        #pragma unroll
        for (int j = 0; j < 4; ++j) {
            int k = l32 * 4 + j;
            if (k < MAX_NUM_SEG) { offs[base + k] = run; run += v[j]; }
        }
    }
    __syncthreads();

    // counts: 4 consecutive segments per thread (3456 = 864*4)
    int cnt[4] = {0, 0, 0, 0};
    int csum = 0;
    if (tid < N_SEG / 4) {
        float4 sc4 = ((const float4*)scales_u)[tid];
        float scv[4] = {sc4.x, sc4.y, sc4.z, sc4.w};
        #pragma unroll
        for (int j = 0; j < 4; ++j) {
            int k = tid * 4 + j;
            float scale = scv[j] + 0.5f;
            int T = lenseg[k] - 1;
            int lim = len_seq[k / MAX_NUM_SEG] - 1 - offs[k];
            if (lim < T) T = lim;
            float Tf = (float)T;
            int lo = 0, hi = S_CAND;
            while (lo < hi) {
                int mid = (lo + hi) >> 1;
                // exact IEEE div + floor, matches the reference's predicate
                if (floorf((float)mid / scale) < Tf) lo = mid + 1; else hi = mid;
            }
            cnt[j] = lo; csum += lo;
        }
    }

    // block-wide exclusive scan of csum: wave shfl scan + 16-entry combine
    int lane = tid & 63, wave = tid >> 6;
    int incl = csum;
    #pragma unroll
    for (int d = 1; d < 64; d <<= 1) {
        int o = __shfl_up(incl, d, 64);
        if (lane >= d) incl += o;
    }
    if (lane == 63) wavesum[wave] = incl;
    __syncthreads();
    if (tid == 0) {
        int run = 0;
        #pragma unroll
        for (int w = 0; w < 16; ++w) { int v = wavesum[w]; wavesum[w] = run; run += v; }
        wavesum[16] = run;   // total
    }
    __syncthreads();
    int excl = wavesum[wave] + incl - csum;

    int* seg_start = ws + WS_SEGSTART;
    int* seg_off   = ws + WS_SEGOFF;
    if (tid < N_SEG / 4) {
        int4 st;
        st.x = excl;
        st.y = st.x + cnt[0];
        st.z = st.y + cnt[1];
        st.w = st.z + cnt[2];
        ((int4*)seg_start)[tid] = st;
        // vectorized copy of offsets (3456 = 864*4, same thread range)
        ((int4*)seg_off)[tid] = make_int4(offs[tid * 4], offs[tid * 4 + 1],
                                          offs[tid * 4 + 2], offs[tid * 4 + 3]);
    }
    if (tid == 0) {
        int total = wavesum[16];
        seg_start[N_SEG] = total;
        int rows = total / B_ROWS;
        int M = rows < MAX_LEN_PAD ? rows : MAX_LEN_PAD;
        ws[WS_META + 0] = rows;
        ws[WS_META + 1] = M;
    }
}

// Kernel B: segment-parallel direct scatter + fused zero-fill.
// 2560 blocks x 640 threads. rl = tid/20 in [0,32), q4 = tid%20.
// Scatter: block p owns segments 2p (rl<16) and 2p+1 (rl>=16); for each
// s < cnt_n, compacted index g = seg_start[n]+s lands at out row
// (g/rows, g%rows) — division hoisted to one per lane + incremental carry.
// Zero-fill: this block's 32 output rows where t >= M (out is poisoned).
__global__ __launch_bounds__(640) void scatter_fill_kernel(
    const float* __restrict__ x, const float* __restrict__ scales_u,
    const int* __restrict__ ws, float* __restrict__ out)
{
    const int* meta      = ws + WS_META;
    const int* seg_start = ws + WS_SEGSTART;
    const int* seg_off   = ws + WS_SEGOFF;

    int rows = meta[0];
    int M    = meta[1];
    int tid  = threadIdx.x;
    int rl   = tid / 20;          // 0..31
    int q4   = tid - rl * 20;     // 0..19
    const float4* x4   = (const float4*)x;
    float4*       out4 = (float4*)out;

    int n  = 2 * blockIdx.x + (rl >> 4);   // segment for this half
    int sl = rl & 15;                      // s-lane within segment
    if (n < N_SEG && rows > 0) {
        int s0  = seg_start[n];
        int cnt = seg_start[n + 1] - s0;
        if (cnt > 0) {
            float scale = scales_u[n] + 0.5f;
            int off  = seg_off[n];
            int xrow = (n / MAX_NUM_SEG) * MAX_LEN_PAD;
            // one division per lane; incremental carry inside the loop
            int b_out = s0 / rows;
            int t0    = s0 - b_out * rows;
            for (int s = sl; s < cnt; s += 16) {
                int t = t0 + s;
                int bo = b_out;
                while (t >= rows && bo < B_ROWS) { t -= rows; ++bo; }
                if (bo < B_ROWS && t < MAX_LEN_PAD) {
                    float q  = (float)s / scale;     // exact IEEE, matches ref
                    float fi = floorf(q);
                    float lam = q - fi;
                    int i_fl = (int)fi + off;
                    if (i_fl > MAX_LEN_PAD - 2) i_fl = MAX_LEN_PAD - 2; // ref clip
                    int sb = (xrow + i_fl) * 20 + q4;
                    float4 a = x4[sb];
                    float4 c = x4[sb + 20];
                    float om = 1.0f - lam;
                    float4 r;
                    r.x = om * a.x + lam * c.x;
                    r.y = om * a.y + lam * c.y;
                    r.z = om * a.z + lam * c.z;
                    r.w = om * a.w + lam * c.w;
                    out4[(bo * MAX_LEN_PAD + t) * 20 + q4] = r;
                }
            }
        }
    }

    // zero-fill phase: this block's 32 output rows, where t >= M.
    // R3 bug was `blockIdx.x & 79` (bitmask != % 80). Use true constant
    // modulo — compiler emits a magic-multiply, once per thread.
    int r = blockIdx.x * 32 + rl;
    int t = r % MAX_LEN_PAD;
    if (t >= M) out4[r * 20 + q4] = make_float4(0.f, 0.f, 0.f, 0.f);
}

extern "C" void kernel_launch(void* const* d_in, const int* in_sizes, int n_in,
                              void* d_out, int out_size, void* d_ws, size_t ws_size,
                              hipStream_t stream) {
    (void)in_sizes; (void)n_in; (void)out_size; (void)ws_size;
    const float* x           = (const float*)d_in[0];
    const int*   len_seq     = (const int*)d_in[1];
    const float* scales_u    = (const float*)d_in[2];
    const int*   len_seg_raw = (const int*)d_in[3];
    float* out = (float*)d_out;
    int*   ws  = (int*)d_ws;

    seg_scan_kernel<<<1, 1024, 0, stream>>>(len_seq, scales_u, len_seg_raw, ws);

    // 32*2560 out rows / 32 rows per block = 2560 blocks; blocks 0..1727 also
    // scatter segments 2p, 2p+1 (3456 segments total)
    scatter_fill_kernel<<<2560, 640, 0, stream>>>(x, scales_u, ws, out);
}